// Round 15
// baseline (70.539 us; speedup 1.0000x reference)
//
#include <hip/hip_runtime.h>
#include <hip/hip_bf16.h>

// Problem constants (reference: N=768, D_IN=308, H=100, iterations=1)
// Inputs f32, output f32 (verified round 4). hh==0 on the single iteration,
// so B_W[500:600], B2_Wh, D_W/b are dead.
// Two-launch pipeline: k_fused (computes uu inline for its 10 gathered
// neighbor rows -> no k_uu kernel, no global uu buffer) + k_pair (R11 v6).
#define NW   768
#define HID  100
#define DIN  308
#define RPB  2          // rows per block in k_fused
#define TP   32         // pair-tile edge
#define LDP  108        // padded row stride: mod4==0 (aligned b128)

typedef const float* fp;

// ---------------------------------------------------------------------------
// K2' (fused, now includes ModuleA): per block (2 rows):
//   probe int storage -> gather 10 neighbor indices -> stage vv rows in LDS
//   -> compute uu rows directly into ww (tanh(vv@A_W+A_b), zero if notf)
//   -> bb = tanh(ww@B_W[:500]+B_b) -> oo = tanh(bb@B2_Wo+B2_bo)
//   -> hl/hr for 3 heads -> hlhr row-major.
// ---------------------------------------------------------------------------
__global__ __launch_bounds__(640) void k_fused(
    fp vv, const int* __restrict__ indices, const int* __restrict__ nf,
    fp A_W, fp A_b, fp B_W, fp B_b, fp B2_Wo, fp B2_bo,
    fp W1r, fp b1r, fp W1c, fp b1c, fp W1e, fp b1e,
    float* __restrict__ hlhr) {
    __shared__ __align__(16) float vs[10][DIN];      // 12.3 KB gathered vv rows
    __shared__ __align__(16) float ww[RPB][5 * HID]; // 4 KB  (= gathered uu)
    __shared__ float part[5][RPB][128];              // 5.1 KB
    __shared__ __align__(16) float bbs[RPB][HID];
    __shared__ __align__(16) float oos[RPB][HID];
    __shared__ int flags[8];
    __shared__ int jrow[10];
    __shared__ int notfv[RPB];
    const int tid = threadIdx.x;
    const int i0 = blockIdx.x * RPB;

    // ---- inline probe of integer-tensor storage (768 B of each buffer)
    if (tid < 8) flags[tid] = 0;
    __syncthreads();
    if (tid < 192) {
        const unsigned vn = (unsigned)nf[tid];
        if (vn > 1u) atomicOr(&flags[0], 1);
        if (vn & 0xFEFEFEFEu) atomicOr(&flags[1], 1);
        if ((tid & 1) && vn) atomicOr(&flags[2], 1);
        if (!(tid & 1) && vn) atomicOr(&flags[3], 1);
        const unsigned vi = (unsigned)indices[tid];
        if ((tid & 1) && vi) atomicOr(&flags[4], 1);
        if (!(tid & 1) && vi) atomicOr(&flags[5], 1);
    }
    __syncthreads();
    if (tid == 0) {
        int m = 0;
        if (!flags[1] && flags[0]) m = 1;            // packed uint8 bools
        else if (!flags[2] && flags[3]) m = 2;       // int64 per element
        flags[6] = m;
        flags[7] = (!flags[4] && flags[5]) ? 1 : 0;  // idx int64?
    }
    __syncthreads();
    const int mnf = flags[6], midx = flags[7];

    // ---- gather the 10 neighbor indices + not_found flags
    if (tid < 10) {
        const int r = tid / 5, q = tid % 5;
        const int i = i0 + r;
        int j = midx ? indices[2 * (i * 5 + q)] : indices[i * 5 + q];
        j = (j < 0) ? 0 : ((j >= NW) ? NW - 1 : j);
        jrow[tid] = j;
    }
    if (tid < RPB) {
        const int i = i0 + tid;
        notfv[tid] = (mnf == 1) ? (((const unsigned char*)nf)[i] != 0)
                   : (mnf == 2) ? (nf[2 * i] != 0)
                                : (nf[i] != 0);
    }
    __syncthreads();

    // ---- stage the 10 vv rows (coalesced)
    for (int t = tid; t < 10 * DIN; t += 640) {
        const int s = t / DIN, k = t % DIN;
        vs[s][k] = vv[jrow[s] * DIN + k];
    }
    __syncthreads();

    // ---- ModuleA inline: ww[r][q*100+c] = tanh(vs[s]@A_W[:,c]+A_b[c]) or 0
    {
        const int s = tid >> 6;          // slot 0..9
        const int lane = tid & 63;
        const int r = s / 5, q = s % 5;
        const bool nz = (notfv[r] == 0);
        for (int c = lane; c < HID; c += 64) {
            float acc = A_b[c];
#pragma unroll 7
            for (int k = 0; k < DIN; ++k)
                acc = fmaf(vs[s][k], A_W[k * HID + c], acc);
            ww[r][q * HID + c] = nz ? tanhf(acc) : 0.f;
        }
    }
    __syncthreads();

    const int c = tid % 128;
    const int s = tid / 128;        // 0..4

    // ---- B-stage: k-slice of 100, float4 LDS reads over k
    {
        float a0 = 0.f, a1 = 0.f;
        if (c < HID) {
            const int k0 = s * 100;
#pragma unroll 5
            for (int k = k0; k < k0 + 100; k += 4) {
                const float4 w0 = *(const float4*)&ww[0][k];
                const float4 w1 = *(const float4*)&ww[1][k];
                const float b0 = B_W[(k + 0) * HID + c];
                const float b1v = B_W[(k + 1) * HID + c];
                const float b2v = B_W[(k + 2) * HID + c];
                const float b3 = B_W[(k + 3) * HID + c];
                a0 = fmaf(w0.x, b0, a0); a1 = fmaf(w1.x, b0, a1);
                a0 = fmaf(w0.y, b1v, a0); a1 = fmaf(w1.y, b1v, a1);
                a0 = fmaf(w0.z, b2v, a0); a1 = fmaf(w1.z, b2v, a1);
                a0 = fmaf(w0.w, b3, a0); a1 = fmaf(w1.w, b3, a1);
            }
        }
        part[s][0][c] = a0; part[s][1][c] = a1;
    }
    __syncthreads();
    for (int t = tid; t < RPB * HID; t += 640) {
        const int r = t / HID, cc = t % HID;
        float acc = B_b[cc];
#pragma unroll
        for (int s2 = 0; s2 < 5; ++s2) acc += part[s2][r][cc];
        bbs[r][cc] = tanhf(acc);
    }
    __syncthreads();

    // ---- oo-stage: k-slice of 20
    {
        float a0 = 0.f, a1 = 0.f;
        if (c < HID) {
            const int k0 = s * 20;
#pragma unroll 5
            for (int k = k0; k < k0 + 20; k += 4) {
                const float4 w0 = *(const float4*)&bbs[0][k];
                const float4 w1 = *(const float4*)&bbs[1][k];
                const float b0 = B2_Wo[(k + 0) * HID + c];
                const float b1v = B2_Wo[(k + 1) * HID + c];
                const float b2v = B2_Wo[(k + 2) * HID + c];
                const float b3 = B2_Wo[(k + 3) * HID + c];
                a0 = fmaf(w0.x, b0, a0); a1 = fmaf(w1.x, b0, a1);
                a0 = fmaf(w0.y, b1v, a0); a1 = fmaf(w1.y, b1v, a1);
                a0 = fmaf(w0.z, b2v, a0); a1 = fmaf(w1.z, b2v, a1);
                a0 = fmaf(w0.w, b3, a0); a1 = fmaf(w1.w, b3, a1);
            }
        }
        part[s][0][c] = a0; part[s][1][c] = a1;
    }
    __syncthreads();
    for (int t = tid; t < RPB * HID; t += 640) {
        const int r = t / HID, cc = t % HID;
        float acc = B2_bo[cc];
#pragma unroll
        for (int s2 = 0; s2 < 5; ++s2) acc += part[s2][r][cc];
        oos[r][cc] = tanhf(acc);
    }
    __syncthreads();

    // ---- W1-stage: 600 outputs, K=100; row-major hlhr write
    if (tid < 600) {
        const int ho = tid / HID;
        const int cc = tid % HID;
        const int h = ho >> 1, half = ho & 1;
        fp W1 = (h == 0) ? W1r : ((h == 1) ? W1c : W1e);
        fp b1 = (h == 0) ? b1r : ((h == 1) ? b1c : b1e);
        const float bias = half ? 0.f : b1[cc];
        float a0 = bias, a1 = bias;
        const float* Wp = W1 + half * HID * HID;
#pragma unroll 5
        for (int k = 0; k < HID; k += 4) {
            const float4 o0 = *(const float4*)&oos[0][k];
            const float4 o1 = *(const float4*)&oos[1][k];
            const float b0 = Wp[(k + 0) * HID + cc];
            const float b1v = Wp[(k + 1) * HID + cc];
            const float b2v = Wp[(k + 2) * HID + cc];
            const float b3 = Wp[(k + 3) * HID + cc];
            a0 = fmaf(o0.x, b0, a0); a1 = fmaf(o1.x, b0, a1);
            a0 = fmaf(o0.y, b1v, a0); a1 = fmaf(o1.y, b1v, a1);
            a0 = fmaf(o0.z, b2v, a0); a1 = fmaf(o1.z, b2v, a1);
            a0 = fmaf(o0.w, b3, a0); a1 = fmaf(o1.w, b3, a1);
        }
        hlhr[(size_t)ho * (NW * HID) + (size_t)(i0 + 0) * HID + cc] = a0;
        hlhr[(size_t)ho * (NW * HID) + (size_t)(i0 + 1) * HID + cc] = a1;
    }
}

// ---------------------------------------------------------------------------
// K3 v6 (best-measured, R11): out[h][i][j][:] = relu(hl_i + hr_j)@W2h + b2h
// 32x32 tile / block (256 thr), 2x2 micro-tile, row-major LDS [32][108].
// LDS 28.4 KB -> 5 blocks/CU.
// ---------------------------------------------------------------------------
__global__ __launch_bounds__(256, 4) void k_pair(
    const float* __restrict__ hlhr,
    fp W2r, fp b2r, fp W2c, fp b2c, fp W2e, fp b2e,
    float* __restrict__ out) {
    __shared__ __align__(16) float hlS[TP][LDP];
    __shared__ __align__(16) float hrS[TP][LDP];
    __shared__ __align__(16) float w2a[HID];
    __shared__ __align__(16) float w2b[HID];

    const int h  = blockIdx.z;
    const int i0 = blockIdx.y * TP;
    const int j0 = blockIdx.x * TP;
    const float* hl = hlhr + (size_t)(h * 2 + 0) * (NW * HID) + (size_t)i0 * HID;
    const float* hr = hlhr + (size_t)(h * 2 + 1) * (NW * HID) + (size_t)j0 * HID;
    fp W2 = (h == 0) ? W2r : ((h == 1) ? W2c : W2e);
    fp b2 = (h == 0) ? b2r : ((h == 1) ? b2c : b2e);

    for (int t = threadIdx.x; t < TP * HID; t += 256) {
        const int r = t / HID, c = t % HID;
        hlS[r][c] = hl[t];
        hrS[r][c] = hr[t];
    }
    if (threadIdx.x < HID) {
        w2a[threadIdx.x] = W2[2 * threadIdx.x];
        w2b[threadIdx.x] = W2[2 * threadIdx.x + 1];
    }
    __syncthreads();

    const int tx = threadIdx.x & 15;
    const int ty = threadIdx.x >> 4;
    float acc0[2][2] = {};
    float acc1[2][2] = {};

#pragma unroll 5
    for (int kb = 0; kb < HID; kb += 4) {
        const float4 a0 = *(const float4*)&hlS[ty * 2 + 0][kb];
        const float4 a1 = *(const float4*)&hlS[ty * 2 + 1][kb];
        const float4 r0 = *(const float4*)&hrS[tx * 2 + 0][kb];
        const float4 r1 = *(const float4*)&hrS[tx * 2 + 1][kb];
        const float4 wa = *(const float4*)&w2a[kb];
        const float4 wb = *(const float4*)&w2b[kb];
#define STEP(cmp)                                                              \
        {                                                                      \
            const float h00 = fmaxf(a0.cmp + r0.cmp, 0.f);                     \
            const float h01 = fmaxf(a0.cmp + r1.cmp, 0.f);                     \
            const float h10 = fmaxf(a1.cmp + r0.cmp, 0.f);                     \
            const float h11 = fmaxf(a1.cmp + r1.cmp, 0.f);                     \
            acc0[0][0] = fmaf(h00, wa.cmp, acc0[0][0]);                        \
            acc1[0][0] = fmaf(h00, wb.cmp, acc1[0][0]);                        \
            acc0[0][1] = fmaf(h01, wa.cmp, acc0[0][1]);                        \
            acc1[0][1] = fmaf(h01, wb.cmp, acc1[0][1]);                        \
            acc0[1][0] = fmaf(h10, wa.cmp, acc0[1][0]);                        \
            acc1[1][0] = fmaf(h10, wb.cmp, acc1[1][0]);                        \
            acc0[1][1] = fmaf(h11, wa.cmp, acc0[1][1]);                        \
            acc1[1][1] = fmaf(h11, wb.cmp, acc1[1][1]);                        \
        }
        STEP(x) STEP(y) STEP(z) STEP(w)
#undef STEP
    }

    const float b20 = b2[0];
    const float b21 = b2[1];
#pragma unroll
    for (int ii = 0; ii < 2; ++ii) {
        const int i = i0 + ty * 2 + ii;
        const size_t rowo = ((size_t)(h * NW + i) * NW + j0 + tx * 2) * 2;
        float4 v;
        v.x = acc0[ii][0] + b20; v.y = acc1[ii][0] + b21;
        v.z = acc0[ii][1] + b20; v.w = acc1[ii][1] + b21;
        *reinterpret_cast<float4*>(out + rowo) = v;
    }
}

// ---------------------------------------------------------------------------
extern "C" void kernel_launch(void* const* d_in, const int* in_sizes, int n_in,
                              void* d_out, int out_size, void* d_ws,
                              size_t ws_size, hipStream_t stream) {
    int i_vv = -1, i_idx = -1, i_nf = -1, i_AW = -1, i_BW = -1;
    int tens[3] = {-1, -1, -1}; int n10 = 0;   // B2_Wo, B2_Wh, D_W
    int w1s[3]  = {-1, -1, -1}; int n20 = 0;
    int w2s_[3] = {-1, -1, -1}; int n200 = 0;
    int b100[8] = {-1, -1, -1, -1, -1, -1, -1, -1}; int nb = 0;
    int b2s[3]  = {-1, -1, -1}; int nb2 = 0;
    for (int i = 0; i < n_in; ++i) {
        switch (in_sizes[i]) {
            case 236544: i_vv = i; break;
            case 3840:   i_idx = i; break;
            case 768:    i_nf = i; break;
            case 30800:  i_AW = i; break;
            case 60000:  i_BW = i; break;
            case 10000:  if (n10 < 3) tens[n10++] = i; break;
            case 20000:  if (n20 < 3) w1s[n20++] = i; break;
            case 200:    if (n200 < 3) w2s_[n200++] = i; break;
            case 100:    if (nb < 8) b100[nb++] = i; break;
            case 2:      if (nb2 < 3) b2s[nb2++] = i; break;
            default: break;  // num_words (size 1)
        }
    }
    fp vv          = (fp)d_in[i_vv];
    const int* idx = (const int*)d_in[i_idx];
    const int* nf  = (const int*)d_in[i_nf];
    fp A_W = (fp)d_in[i_AW],      A_b   = (fp)d_in[b100[0]];
    fp B_W = (fp)d_in[i_BW],      B_b   = (fp)d_in[b100[1]];
    fp B2_Wo = (fp)d_in[tens[0]], B2_bo = (fp)d_in[b100[2]];
    fp W1r = (fp)d_in[w1s[0]], b1r = (fp)d_in[b100[5]];
    fp W1c = (fp)d_in[w1s[1]], b1c = (fp)d_in[b100[6]];
    fp W1e = (fp)d_in[w1s[2]], b1e = (fp)d_in[b100[7]];
    fp W2r = (fp)d_in[w2s_[0]], b2r = (fp)d_in[b2s[0]];
    fp W2c = (fp)d_in[w2s_[1]], b2c = (fp)d_in[b2s[1]];
    fp W2e = (fp)d_in[w2s_[2]], b2e = (fp)d_in[b2s[2]];

    float* out = (float*)d_out;

    float* ws   = (float*)d_ws;
    float* hlhr = ws;                       // [6][768][100] f32

    k_fused<<<NW / RPB, 640, 0, stream>>>(vv, idx, nf, A_W, A_b, B_W, B_b,
                                          B2_Wo, B2_bo,
                                          W1r, b1r, W1c, b1c, W1e, b1e, hlhr);
    dim3 grid(NW / TP, NW / TP, 3);
    k_pair<<<grid, 256, 0, stream>>>(hlhr, W2r, b2r, W2c, b2c, W2e, b2e, out);
}

// Round 16
// 47.245 us; speedup vs baseline: 1.4930x; 1.4930x over previous
//
#include <hip/hip_runtime.h>
#include <hip/hip_bf16.h>

// Problem constants (reference: N=768, D_IN=308, H=100, iterations=1)
// Inputs f32, output f32 (verified round 4). hh==0 on the single iteration,
// so B_W[500:600], B2_Wh, D_W/b are dead.
// Three-launch pipeline (structural floor): k_uu + k_fused(RPB=3) + k_pair(v6).
#define NW   768
#define HID  100
#define DIN  308
#define RPU  2          // rows per block in k_uu (proven)
#define RPF  3          // rows per block in k_fused: 256 blocks = 1/CU,
                        // weight re-read 184->123 MB L2
#define TP   32         // pair-tile edge
#define LDP  108        // padded row stride: mod4==0 (aligned b128)

typedef const float* fp;

// ---------------------------------------------------------------------------
// K1: uu = tanh(vv @ A_W + A_b).  (identical to rounds 7-14)
// ---------------------------------------------------------------------------
__global__ __launch_bounds__(512) void k_uu(fp vv, fp A_W, fp A_b,
                                            float* __restrict__ uu) {
    __shared__ float vs[RPU][DIN];
    __shared__ float part[4][RPU][128];
    const int i0 = blockIdx.x * RPU;
    for (int t = threadIdx.x; t < RPU * DIN; t += 512) {
        const int r = t / DIN, k = t % DIN;
        vs[r][k] = vv[(i0 + r) * DIN + k];
    }
    __syncthreads();
    const int c = threadIdx.x & 127;
    const int s = threadIdx.x >> 7;
    float a0 = 0.f, a1 = 0.f;
    if (c < HID) {
        const int k0 = s * 77;
#pragma unroll 11
        for (int k = k0; k < k0 + 77; ++k) {
            const float w = A_W[k * HID + c];
            a0 = fmaf(vs[0][k], w, a0);
            a1 = fmaf(vs[1][k], w, a1);
        }
    }
    part[s][0][c] = a0; part[s][1][c] = a1;
    __syncthreads();
    for (int t = threadIdx.x; t < RPU * HID; t += 512) {
        const int r = t / HID, cc = t % HID;
        float acc = A_b[cc];
#pragma unroll
        for (int s2 = 0; s2 < 4; ++s2) acc += part[s2][r][cc];
        uu[(i0 + r) * HID + cc] = tanhf(acc);
    }
}

// ---------------------------------------------------------------------------
// K2 (fused, RPB=3): probe -> gather ww -> bb -> oo -> hl/hr for 3 heads.
// 256 blocks (1/CU), 640 thr = 5 k-slices x 128 cols; 3 rows amortize each
// weight load (load:FMA 1:3 vs 1:2).
// ---------------------------------------------------------------------------
__global__ __launch_bounds__(640) void k_fused(
    const float* __restrict__ uu, const int* __restrict__ indices,
    const int* __restrict__ nf,
    fp B_W, fp B_b, fp B2_Wo, fp B2_bo,
    fp W1r, fp b1r, fp W1c, fp b1c, fp W1e, fp b1e,
    float* __restrict__ hlhr) {
    __shared__ __align__(16) float ww[RPF][5 * HID];   // 6 KB
    __shared__ float part[5][RPF][128];                // 7.7 KB
    __shared__ __align__(16) float bbs[RPF][HID];
    __shared__ __align__(16) float oos[RPF][HID];
    __shared__ int flags[6];
    __shared__ int smode[2];
    const int tid = threadIdx.x;

    if (tid < 6) flags[tid] = 0;
    __syncthreads();
    if (tid < 192) {
        const unsigned vn = (unsigned)nf[tid];
        if (vn > 1u) atomicOr(&flags[0], 1);
        if (vn & 0xFEFEFEFEu) atomicOr(&flags[1], 1);
        if ((tid & 1) && vn) atomicOr(&flags[2], 1);
        if (!(tid & 1) && vn) atomicOr(&flags[3], 1);
        const unsigned vi = (unsigned)indices[tid];
        if ((tid & 1) && vi) atomicOr(&flags[4], 1);
        if (!(tid & 1) && vi) atomicOr(&flags[5], 1);
    }
    __syncthreads();
    if (tid == 0) {
        int m = 0;
        if (!flags[1] && flags[0]) m = 1;            // packed uint8 bools
        else if (!flags[2] && flags[3]) m = 2;       // int64 per element
        smode[0] = m;
        smode[1] = (!flags[4] && flags[5]) ? 1 : 0;  // idx int64?
    }
    __syncthreads();
    const int mnf = smode[0], midx = smode[1];

    const int i0 = blockIdx.x * RPF;
    for (int t = tid; t < RPF * 5 * HID; t += 640) {
        const int r = t / (5 * HID), u = t % (5 * HID);
        const int i = i0 + r;
        const bool notf = (mnf == 1) ? (((const unsigned char*)nf)[i] != 0)
                        : (mnf == 2) ? (nf[2 * i] != 0)
                                     : (nf[i] != 0);
        const int q = u / HID, cc = u % HID;
        int j = midx ? indices[2 * (i * 5 + q)] : indices[i * 5 + q];
        j = (j < 0) ? 0 : ((j >= NW) ? NW - 1 : j);
        ww[r][u] = notf ? 0.f : uu[j * HID + cc];
    }
    __syncthreads();

    const int c = tid % 128;
    const int s = tid / 128;        // 0..4

    // ---- B-stage: k-slice of 100, float4 LDS reads over k, 3 rows/thread
    {
        float a0 = 0.f, a1 = 0.f, a2 = 0.f;
        if (c < HID) {
            const int k0 = s * 100;
#pragma unroll 5
            for (int k = k0; k < k0 + 100; k += 4) {
                const float4 w0 = *(const float4*)&ww[0][k];
                const float4 w1 = *(const float4*)&ww[1][k];
                const float4 w2 = *(const float4*)&ww[2][k];
                const float b0 = B_W[(k + 0) * HID + c];
                const float b1v = B_W[(k + 1) * HID + c];
                const float b2v = B_W[(k + 2) * HID + c];
                const float b3 = B_W[(k + 3) * HID + c];
                a0 = fmaf(w0.x, b0, a0); a1 = fmaf(w1.x, b0, a1); a2 = fmaf(w2.x, b0, a2);
                a0 = fmaf(w0.y, b1v, a0); a1 = fmaf(w1.y, b1v, a1); a2 = fmaf(w2.y, b1v, a2);
                a0 = fmaf(w0.z, b2v, a0); a1 = fmaf(w1.z, b2v, a1); a2 = fmaf(w2.z, b2v, a2);
                a0 = fmaf(w0.w, b3, a0); a1 = fmaf(w1.w, b3, a1); a2 = fmaf(w2.w, b3, a2);
            }
        }
        part[s][0][c] = a0; part[s][1][c] = a1; part[s][2][c] = a2;
    }
    __syncthreads();
    for (int t = tid; t < RPF * HID; t += 640) {
        const int r = t / HID, cc = t % HID;
        float acc = B_b[cc];
#pragma unroll
        for (int s2 = 0; s2 < 5; ++s2) acc += part[s2][r][cc];
        bbs[r][cc] = tanhf(acc);
    }
    __syncthreads();

    // ---- oo-stage: k-slice of 20
    {
        float a0 = 0.f, a1 = 0.f, a2 = 0.f;
        if (c < HID) {
            const int k0 = s * 20;
#pragma unroll 5
            for (int k = k0; k < k0 + 20; k += 4) {
                const float4 w0 = *(const float4*)&bbs[0][k];
                const float4 w1 = *(const float4*)&bbs[1][k];
                const float4 w2 = *(const float4*)&bbs[2][k];
                const float b0 = B2_Wo[(k + 0) * HID + c];
                const float b1v = B2_Wo[(k + 1) * HID + c];
                const float b2v = B2_Wo[(k + 2) * HID + c];
                const float b3 = B2_Wo[(k + 3) * HID + c];
                a0 = fmaf(w0.x, b0, a0); a1 = fmaf(w1.x, b0, a1); a2 = fmaf(w2.x, b0, a2);
                a0 = fmaf(w0.y, b1v, a0); a1 = fmaf(w1.y, b1v, a1); a2 = fmaf(w2.y, b1v, a2);
                a0 = fmaf(w0.z, b2v, a0); a1 = fmaf(w1.z, b2v, a1); a2 = fmaf(w2.z, b2v, a2);
                a0 = fmaf(w0.w, b3, a0); a1 = fmaf(w1.w, b3, a1); a2 = fmaf(w2.w, b3, a2);
            }
        }
        part[s][0][c] = a0; part[s][1][c] = a1; part[s][2][c] = a2;
    }
    __syncthreads();
    for (int t = tid; t < RPF * HID; t += 640) {
        const int r = t / HID, cc = t % HID;
        float acc = B2_bo[cc];
#pragma unroll
        for (int s2 = 0; s2 < 5; ++s2) acc += part[s2][r][cc];
        oos[r][cc] = tanhf(acc);
    }
    __syncthreads();

    // ---- W1-stage: 600 outputs, K=100; row-major hlhr write (3 rows)
    if (tid < 600) {
        const int ho = tid / HID;
        const int cc = tid % HID;
        const int h = ho >> 1, half = ho & 1;
        fp W1 = (h == 0) ? W1r : ((h == 1) ? W1c : W1e);
        fp b1 = (h == 0) ? b1r : ((h == 1) ? b1c : b1e);
        const float bias = half ? 0.f : b1[cc];
        float a0 = bias, a1 = bias, a2 = bias;
        const float* Wp = W1 + half * HID * HID;
#pragma unroll 5
        for (int k = 0; k < HID; k += 4) {
            const float4 o0 = *(const float4*)&oos[0][k];
            const float4 o1 = *(const float4*)&oos[1][k];
            const float4 o2 = *(const float4*)&oos[2][k];
            const float b0 = Wp[(k + 0) * HID + cc];
            const float b1v = Wp[(k + 1) * HID + cc];
            const float b2v = Wp[(k + 2) * HID + cc];
            const float b3 = Wp[(k + 3) * HID + cc];
            a0 = fmaf(o0.x, b0, a0); a1 = fmaf(o1.x, b0, a1); a2 = fmaf(o2.x, b0, a2);
            a0 = fmaf(o0.y, b1v, a0); a1 = fmaf(o1.y, b1v, a1); a2 = fmaf(o2.y, b1v, a2);
            a0 = fmaf(o0.z, b2v, a0); a1 = fmaf(o1.z, b2v, a1); a2 = fmaf(o2.z, b2v, a2);
            a0 = fmaf(o0.w, b3, a0); a1 = fmaf(o1.w, b3, a1); a2 = fmaf(o2.w, b3, a2);
        }
        const size_t base = (size_t)ho * (NW * HID);
        hlhr[base + (size_t)(i0 + 0) * HID + cc] = a0;
        hlhr[base + (size_t)(i0 + 1) * HID + cc] = a1;
        hlhr[base + (size_t)(i0 + 2) * HID + cc] = a2;
    }
}

// ---------------------------------------------------------------------------
// K3 v6 (best-measured, R11): out[h][i][j][:] = relu(hl_i + hr_j)@W2h + b2h
// 32x32 tile / block (256 thr), 2x2 micro-tile, row-major LDS [32][108].
// LDS 28.4 KB -> 5 blocks/CU.
// ---------------------------------------------------------------------------
__global__ __launch_bounds__(256, 4) void k_pair(
    const float* __restrict__ hlhr,
    fp W2r, fp b2r, fp W2c, fp b2c, fp W2e, fp b2e,
    float* __restrict__ out) {
    __shared__ __align__(16) float hlS[TP][LDP];
    __shared__ __align__(16) float hrS[TP][LDP];
    __shared__ __align__(16) float w2a[HID];
    __shared__ __align__(16) float w2b[HID];

    const int h  = blockIdx.z;
    const int i0 = blockIdx.y * TP;
    const int j0 = blockIdx.x * TP;
    const float* hl = hlhr + (size_t)(h * 2 + 0) * (NW * HID) + (size_t)i0 * HID;
    const float* hr = hlhr + (size_t)(h * 2 + 1) * (NW * HID) + (size_t)j0 * HID;
    fp W2 = (h == 0) ? W2r : ((h == 1) ? W2c : W2e);
    fp b2 = (h == 0) ? b2r : ((h == 1) ? b2c : b2e);

    for (int t = threadIdx.x; t < TP * HID; t += 256) {
        const int r = t / HID, c = t % HID;
        hlS[r][c] = hl[t];
        hrS[r][c] = hr[t];
    }
    if (threadIdx.x < HID) {
        w2a[threadIdx.x] = W2[2 * threadIdx.x];
        w2b[threadIdx.x] = W2[2 * threadIdx.x + 1];
    }
    __syncthreads();

    const int tx = threadIdx.x & 15;
    const int ty = threadIdx.x >> 4;
    float acc0[2][2] = {};
    float acc1[2][2] = {};

#pragma unroll 5
    for (int kb = 0; kb < HID; kb += 4) {
        const float4 a0 = *(const float4*)&hlS[ty * 2 + 0][kb];
        const float4 a1 = *(const float4*)&hlS[ty * 2 + 1][kb];
        const float4 r0 = *(const float4*)&hrS[tx * 2 + 0][kb];
        const float4 r1 = *(const float4*)&hrS[tx * 2 + 1][kb];
        const float4 wa = *(const float4*)&w2a[kb];
        const float4 wb = *(const float4*)&w2b[kb];
#define STEP(cmp)                                                              \
        {                                                                      \
            const float h00 = fmaxf(a0.cmp + r0.cmp, 0.f);                     \
            const float h01 = fmaxf(a0.cmp + r1.cmp, 0.f);                     \
            const float h10 = fmaxf(a1.cmp + r0.cmp, 0.f);                     \
            const float h11 = fmaxf(a1.cmp + r1.cmp, 0.f);                     \
            acc0[0][0] = fmaf(h00, wa.cmp, acc0[0][0]);                        \
            acc1[0][0] = fmaf(h00, wb.cmp, acc1[0][0]);                        \
            acc0[0][1] = fmaf(h01, wa.cmp, acc0[0][1]);                        \
            acc1[0][1] = fmaf(h01, wb.cmp, acc1[0][1]);                        \
            acc0[1][0] = fmaf(h10, wa.cmp, acc0[1][0]);                        \
            acc1[1][0] = fmaf(h10, wb.cmp, acc1[1][0]);                        \
            acc0[1][1] = fmaf(h11, wa.cmp, acc0[1][1]);                        \
            acc1[1][1] = fmaf(h11, wb.cmp, acc1[1][1]);                        \
        }
        STEP(x) STEP(y) STEP(z) STEP(w)
#undef STEP
    }

    const float b20 = b2[0];
    const float b21 = b2[1];
#pragma unroll
    for (int ii = 0; ii < 2; ++ii) {
        const int i = i0 + ty * 2 + ii;
        const size_t rowo = ((size_t)(h * NW + i) * NW + j0 + tx * 2) * 2;
        float4 v;
        v.x = acc0[ii][0] + b20; v.y = acc1[ii][0] + b21;
        v.z = acc0[ii][1] + b20; v.w = acc1[ii][1] + b21;
        *reinterpret_cast<float4*>(out + rowo) = v;
    }
}

// ---------------------------------------------------------------------------
extern "C" void kernel_launch(void* const* d_in, const int* in_sizes, int n_in,
                              void* d_out, int out_size, void* d_ws,
                              size_t ws_size, hipStream_t stream) {
    int i_vv = -1, i_idx = -1, i_nf = -1, i_AW = -1, i_BW = -1;
    int tens[3] = {-1, -1, -1}; int n10 = 0;   // B2_Wo, B2_Wh, D_W
    int w1s[3]  = {-1, -1, -1}; int n20 = 0;
    int w2s_[3] = {-1, -1, -1}; int n200 = 0;
    int b100[8] = {-1, -1, -1, -1, -1, -1, -1, -1}; int nb = 0;
    int b2s[3]  = {-1, -1, -1}; int nb2 = 0;
    for (int i = 0; i < n_in; ++i) {
        switch (in_sizes[i]) {
            case 236544: i_vv = i; break;
            case 3840:   i_idx = i; break;
            case 768:    i_nf = i; break;
            case 30800:  i_AW = i; break;
            case 60000:  i_BW = i; break;
            case 10000:  if (n10 < 3) tens[n10++] = i; break;
            case 20000:  if (n20 < 3) w1s[n20++] = i; break;
            case 200:    if (n200 < 3) w2s_[n200++] = i; break;
            case 100:    if (nb < 8) b100[nb++] = i; break;
            case 2:      if (nb2 < 3) b2s[nb2++] = i; break;
            default: break;  // num_words (size 1)
        }
    }
    fp vv          = (fp)d_in[i_vv];
    const int* idx = (const int*)d_in[i_idx];
    const int* nf  = (const int*)d_in[i_nf];
    fp A_W = (fp)d_in[i_AW],      A_b   = (fp)d_in[b100[0]];
    fp B_W = (fp)d_in[i_BW],      B_b   = (fp)d_in[b100[1]];
    fp B2_Wo = (fp)d_in[tens[0]], B2_bo = (fp)d_in[b100[2]];
    fp W1r = (fp)d_in[w1s[0]], b1r = (fp)d_in[b100[5]];
    fp W1c = (fp)d_in[w1s[1]], b1c = (fp)d_in[b100[6]];
    fp W1e = (fp)d_in[w1s[2]], b1e = (fp)d_in[b100[7]];
    fp W2r = (fp)d_in[w2s_[0]], b2r = (fp)d_in[b2s[0]];
    fp W2c = (fp)d_in[w2s_[1]], b2c = (fp)d_in[b2s[1]];
    fp W2e = (fp)d_in[w2s_[2]], b2e = (fp)d_in[b2s[2]];

    float* out = (float*)d_out;

    float* ws   = (float*)d_ws;
    float* uu   = ws;                       // 768*100 f32
    float* hlhr = ws + NW * HID;            // [6][768][100] f32

    k_uu<<<NW / RPU, 512, 0, stream>>>(vv, A_W, A_b, uu);
    k_fused<<<NW / RPF, 640, 0, stream>>>(uu, idx, nf, B_W, B_b,
                                          B2_Wo, B2_bo,
                                          W1r, b1r, W1c, b1c, W1e, b1e, hlhr);
    dim3 grid(NW / TP, NW / TP, 3);
    k_pair<<<grid, 256, 0, stream>>>(hlhr, W2r, b2r, W2c, b2c, W2e, b2e, out);
}